// Round 1
// baseline (14534.323 us; speedup 1.0000x reference)
//
#include <hip/hip_runtime.h>

// GCN_21534966022931 — 2-layer multi-behavior GraphConv, f32 baseline.
// Structure per layer:
//   per behavior t: one fused edge pass (fwd msg, rev msg, se, de in ONE read
//   of edge features), node GEMV+leaky+weighted-accumulate, in-place edge
//   update GEMV. Edge features mutate the input buffers (restored by harness).

constexpr int NU_ = 100000;
constexpr int NI_ = 50000;
constexpr int EB_ = 500000;
constexpr int EC_ = 1000000;
constexpr int EP_ = 2000000;
constexpr float SLOPE_ = 0.01f;
constexpr float SCALE_A = 0.0045f;
constexpr float SCALE_B = 0.0045f;

__device__ __forceinline__ float leakyf(float x) {
  return x >= 0.0f ? x : SLOPE_ * x;
}

__global__ void k_deg_count(const int* __restrict__ U, const int* __restrict__ V,
                            float* __restrict__ du, float* __restrict__ dv, int E) {
  int i = blockIdx.x * blockDim.x + threadIdx.x;
  if (i < E) {
    atomicAdd(du + U[i], 1.0f);
    atomicAdd(dv + V[i], 1.0f);
  }
}

__global__ void k_deg_finish(float* __restrict__ d, float* __restrict__ nrm, int n) {
  int i = blockIdx.x * blockDim.x + threadIdx.x;
  if (i < n) {
    float c = fmaxf(d[i], 1.0f);   // DGL clamp to min degree 1
    d[i] = c;
    nrm[i] = rsqrtf(c);
  }
}

__global__ void k_init_nodes(const float* __restrict__ emb, float scale,
                             float* __restrict__ cur, float* __restrict__ acc, int n) {
  int i = blockIdx.x * blockDim.x + threadIdx.x;
  if (i < n) {
    float x = emb[i] * scale;
    cur[i] = x;
    acc[i] = x;
  }
}

// One fused pass over edges of one behavior: wave per edge, lane per feature.
// Produces: agg_dst[v] += src[u]*nu[u]*e   (forward gconv message)
//           agg_src[u] += dst[v]*nv[v]*e   (reverse gconv message)
//           se[u] += e ; de[v] += e        (update_edge segment sums)
__global__ void __launch_bounds__(256)
k_edge_pass(const int* __restrict__ U, const int* __restrict__ V,
            const float* __restrict__ EF, float escale,
            const float* __restrict__ src, const float* __restrict__ dst,
            const float* __restrict__ nu, const float* __restrict__ nv,
            float* __restrict__ agg_dst, float* __restrict__ agg_src,
            float* __restrict__ se, float* __restrict__ de, int E) {
  int gid = blockIdx.x * 256 + threadIdx.x;
  int e = gid >> 6;
  int l = threadIdx.x & 63;
  if (e >= E) return;
  int u = U[e];
  int v = V[e];
  float ev = EF[(size_t)e * 64 + l] * escale;
  float cu = nu[u];
  float cv = nv[v];
  float su = src[u * 64 + l];
  float dv = dst[v * 64 + l];
  atomicAdd(agg_dst + v * 64 + l, su * cu * ev);
  atomicAdd(agg_src + u * 64 + l, dv * cv * ev);
  atomicAdd(se + u * 64 + l, ev);
  atomicAdd(de + v * 64 + l, ev);
}

// out[n] += wt * leaky( (agg[n] @ W) * nrm[n] )  — wave per node, shuffle GEMV
__global__ void __launch_bounds__(256)
k_node_acc(const float* __restrict__ agg, const float* __restrict__ nrm,
           const float* __restrict__ W, float wt,
           float* __restrict__ outv, int N) {
  __shared__ float Ws[64 * 64];
  for (int i = threadIdx.x; i < 64 * 64; i += 256) Ws[i] = W[i];
  __syncthreads();
  int gid = blockIdx.x * 256 + threadIdx.x;
  int n = gid >> 6;
  int l = threadIdx.x & 63;
  if (n >= N) return;
  float a = agg[n * 64 + l];
  float acc = 0.0f;
#pragma unroll
  for (int k = 0; k < 64; ++k) {
    acc += __shfl(a, k) * Ws[k * 64 + l];
  }
  outv[n * 64 + l] += wt * leakyf(acc * nrm[n]);
}

// EF[e] = leaky( ((se[u]+de[v]) / (sd[u]+dd[v])) @ W )  — in-place edge update
__global__ void __launch_bounds__(256)
k_edge_update(const int* __restrict__ U, const int* __restrict__ V,
              const float* __restrict__ se, const float* __restrict__ de,
              const float* __restrict__ sd, const float* __restrict__ dd,
              const float* __restrict__ W,
              float* __restrict__ EF, int E) {
  __shared__ float Ws[64 * 64];
  for (int i = threadIdx.x; i < 64 * 64; i += 256) Ws[i] = W[i];
  __syncthreads();
  int gid = blockIdx.x * 256 + threadIdx.x;
  int e = gid >> 6;
  int l = threadIdx.x & 63;
  if (e >= E) return;
  int u = U[e];
  int v = V[e];
  float inv = 1.0f / (sd[u] + dd[v]);
  float t = (se[u * 64 + l] + de[v * 64 + l]) * inv;
  float acc = 0.0f;
#pragma unroll
  for (int k = 0; k < 64; ++k) {
    acc += __shfl(t, k) * Ws[k * 64 + l];
  }
  EF[(size_t)e * 64 + l] = leakyf(acc);
}

__global__ void k_add(const float* __restrict__ a, float* __restrict__ b, int n) {
  int i = blockIdx.x * blockDim.x + threadIdx.x;
  if (i < n) b[i] += a[i];
}

__global__ void k_scale(float* __restrict__ a, float s, int n) {
  int i = blockIdx.x * blockDim.x + threadIdx.x;
  if (i < n) a[i] *= s;
}

extern "C" void kernel_launch(void* const* d_in, const int* in_sizes, int n_in,
                              void* d_out, int out_size, void* d_ws, size_t ws_size,
                              hipStream_t stream) {
  const float* user_emb = (const float*)d_in[0];
  const float* item_emb = (const float*)d_in[1];
  // Edge features are updated in place (harness restores inputs every launch).
  float* e_feat[3] = {(float*)d_in[2], (float*)d_in[3], (float*)d_in[4]};
  const float* node_W = (const float*)d_in[5];
  const float* edge_W = (const float*)d_in[6];
  const int* eu[3] = {(const int*)d_in[7], (const int*)d_in[9], (const int*)d_in[11]};
  const int* evv[3] = {(const int*)d_in[8], (const int*)d_in[10], (const int*)d_in[12]};
  const int Ecnt[3] = {EB_, EC_, EP_};
  const float wts[3] = {1.0f, 0.5f, 0.25f};

  float* out_src = (float*)d_out;        // [NU,64] running sum -> /3 at end
  float* out_dst = out_src + NU_ * 64;   // [NI,64]

  // workspace carve-up (~157 MB total)
  float* p = (float*)d_ws;
  float* src_cur = p; p += NU_ * 64;
  float* dst_cur = p; p += NI_ * 64;
  float* src_nxt = p; p += NU_ * 64;   // src_nxt+dst_nxt adjacent -> one memset
  float* dst_nxt = p; p += NI_ * 64;
  float* agg_src = p; p += NU_ * 64;   // agg_src+se adjacent -> one memset
  float* se      = p; p += NU_ * 64;
  float* agg_dst = p; p += NI_ * 64;   // agg_dst+de adjacent -> one memset
  float* de      = p; p += NI_ * 64;
  float* degu    = p; p += 3 * NU_;    // degu+degv adjacent -> one memset
  float* degv    = p; p += 3 * NI_;
  float* nrmu    = p; p += 3 * NU_;
  float* nrmv    = p; p += 3 * NI_;

  // ---- degrees (shared by both layers; depend only on indices) ----
  hipMemsetAsync(degu, 0, (size_t)(3 * NU_ + 3 * NI_) * sizeof(float), stream);
  for (int t = 0; t < 3; ++t) {
    k_deg_count<<<(Ecnt[t] + 255) / 256, 256, 0, stream>>>(
        eu[t], evv[t], degu + t * NU_, degv + t * NI_, Ecnt[t]);
  }
  for (int t = 0; t < 3; ++t) {
    k_deg_finish<<<(NU_ + 255) / 256, 256, 0, stream>>>(degu + t * NU_, nrmu + t * NU_, NU_);
    k_deg_finish<<<(NI_ + 255) / 256, 256, 0, stream>>>(degv + t * NI_, nrmv + t * NI_, NI_);
  }

  // ---- init: src0 = A*user, dst0 = A*item; accumulators start at layer-0 vals
  k_init_nodes<<<(NU_ * 64 + 255) / 256, 256, 0, stream>>>(user_emb, SCALE_A, src_cur, out_src, NU_ * 64);
  k_init_nodes<<<(NI_ * 64 + 255) / 256, 256, 0, stream>>>(item_emb, SCALE_A, dst_cur, out_dst, NI_ * 64);

  for (int layer = 0; layer < 2; ++layer) {
    const float* Wn = node_W + layer * 64 * 64;
    const float* We = edge_W + layer * 64 * 64;
    float escale = (layer == 0) ? SCALE_B : 1.0f;  // layer0 reads pristine inputs * B
    hipMemsetAsync(src_nxt, 0, (size_t)(NU_ + NI_) * 64 * sizeof(float), stream);
    for (int t = 0; t < 3; ++t) {
      int E = Ecnt[t];
      hipMemsetAsync(agg_src, 0, (size_t)NU_ * 128 * sizeof(float), stream);
      hipMemsetAsync(agg_dst, 0, (size_t)NI_ * 128 * sizeof(float), stream);
      k_edge_pass<<<(E * 64 + 255) / 256, 256, 0, stream>>>(
          eu[t], evv[t], e_feat[t], escale, src_cur, dst_cur,
          nrmu + t * NU_, nrmv + t * NI_, agg_dst, agg_src, se, de, E);
      k_node_acc<<<(NI_ * 64 + 255) / 256, 256, 0, stream>>>(
          agg_dst, nrmv + t * NI_, Wn, wts[t], dst_nxt, NI_);
      k_node_acc<<<(NU_ * 64 + 255) / 256, 256, 0, stream>>>(
          agg_src, nrmu + t * NU_, Wn, wts[t], src_nxt, NU_);
      k_edge_update<<<(E * 64 + 255) / 256, 256, 0, stream>>>(
          eu[t], evv[t], se, de, degu + t * NU_, degv + t * NI_, We, e_feat[t], E);
    }
    k_add<<<(NU_ * 64 + 255) / 256, 256, 0, stream>>>(src_nxt, out_src, NU_ * 64);
    k_add<<<(NI_ * 64 + 255) / 256, 256, 0, stream>>>(dst_nxt, out_dst, NI_ * 64);
    float* tmp;
    tmp = src_cur; src_cur = src_nxt; src_nxt = tmp;
    tmp = dst_cur; dst_cur = dst_nxt; dst_nxt = tmp;
  }
  k_scale<<<((NU_ + NI_) * 64 + 255) / 256, 256, 0, stream>>>(
      out_src, 1.0f / 3.0f, (NU_ + NI_) * 64);
}

// Round 2
// 8931.791 us; speedup vs baseline: 1.6273x; 1.6273x over previous
//
#include <hip/hip_runtime.h>

// GCN_21534966022931 — R2: replace LDS-pipe-bound shuffle-GEMV with
// register-blocked 64x64-tile GEMM (4x4 acc per thread, ds_read_b128).

constexpr int NU_ = 100000;
constexpr int NI_ = 50000;
constexpr int EB_ = 500000;
constexpr int EC_ = 1000000;
constexpr int EP_ = 2000000;
constexpr float SLOPE_ = 0.01f;
constexpr float SCALE_A = 0.0045f;
constexpr float SCALE_B = 0.0045f;

constexpr int TPAD = 68;  // T-tile row stride (floats): 64+4 kills 4-way bank alias

__device__ __forceinline__ float leakyf(float x) {
  return x >= 0.0f ? x : SLOPE_ * x;
}

__global__ void k_deg_count(const int* __restrict__ U, const int* __restrict__ V,
                            float* __restrict__ du, float* __restrict__ dv, int E) {
  int i = blockIdx.x * blockDim.x + threadIdx.x;
  if (i < E) {
    atomicAdd(du + U[i], 1.0f);
    atomicAdd(dv + V[i], 1.0f);
  }
}

__global__ void k_deg_finish(float* __restrict__ d, float* __restrict__ nrm, int n) {
  int i = blockIdx.x * blockDim.x + threadIdx.x;
  if (i < n) {
    float c = fmaxf(d[i], 1.0f);   // DGL clamp to min degree 1
    d[i] = c;
    nrm[i] = rsqrtf(c);
  }
}

__global__ void k_init_nodes(const float* __restrict__ emb, float scale,
                             float* __restrict__ cur, float* __restrict__ acc, int n) {
  int i = blockIdx.x * blockDim.x + threadIdx.x;
  if (i < n) {
    float x = emb[i] * scale;
    cur[i] = x;
    acc[i] = x;
  }
}

// Fused edge pass: wave per edge, lane per feature.
__global__ void __launch_bounds__(256)
k_edge_pass(const int* __restrict__ U, const int* __restrict__ V,
            const float* __restrict__ EF, float escale,
            const float* __restrict__ src, const float* __restrict__ dst,
            const float* __restrict__ nu, const float* __restrict__ nv,
            float* __restrict__ agg_dst, float* __restrict__ agg_src,
            float* __restrict__ se, float* __restrict__ de, int E) {
  int gid = blockIdx.x * 256 + threadIdx.x;
  int e = gid >> 6;
  int l = threadIdx.x & 63;
  if (e >= E) return;
  int u = U[e];
  int v = V[e];
  float ev = EF[(size_t)e * 64 + l] * escale;
  float cu = nu[u];
  float cv = nv[v];
  float su = src[u * 64 + l];
  float dv = dst[v * 64 + l];
  atomicAdd(agg_dst + v * 64 + l, su * cu * ev);
  atomicAdd(agg_src + u * 64 + l, dv * cv * ev);
  atomicAdd(se + u * 64 + l, ev);
  atomicAdd(de + v * 64 + l, ev);
}

// ---- shared GEMM tile core: Ts[64 rows x 64 k, stride TPAD] @ Ws[64][64] ----
// thread t: edge-group eg = t>>4 (rows eg*4..+3), col-group cg = t&15 (cols cg*4..+3)
__device__ __forceinline__ void tile_gemm_4x4(const float* Ts, const float* Ws,
                                              int eg, int cg, float acc[4][4]) {
#pragma unroll 4
  for (int k = 0; k < 64; k += 4) {
    float4 tv[4];
    float4 wv[4];
#pragma unroll
    for (int i = 0; i < 4; ++i)
      tv[i] = *(const float4*)&Ts[(eg * 4 + i) * TPAD + k];
#pragma unroll
    for (int kk = 0; kk < 4; ++kk)
      wv[kk] = *(const float4*)&Ws[(k + kk) * 64 + cg * 4];
#pragma unroll
    for (int i = 0; i < 4; ++i) {
      acc[i][0] += tv[i].x * wv[0].x + tv[i].y * wv[1].x + tv[i].z * wv[2].x + tv[i].w * wv[3].x;
      acc[i][1] += tv[i].x * wv[0].y + tv[i].y * wv[1].y + tv[i].z * wv[2].y + tv[i].w * wv[3].y;
      acc[i][2] += tv[i].x * wv[0].z + tv[i].y * wv[1].z + tv[i].z * wv[2].z + tv[i].w * wv[3].z;
      acc[i][3] += tv[i].x * wv[0].w + tv[i].y * wv[1].w + tv[i].z * wv[2].w + tv[i].w * wv[3].w;
    }
  }
}

__device__ __forceinline__ void load_W(const float* __restrict__ W, float* Ws) {
  const float4* W4 = (const float4*)W;
  float4* Ws4 = (float4*)Ws;
#pragma unroll
  for (int i = 0; i < 4; ++i) Ws4[threadIdx.x + 256 * i] = W4[threadIdx.x + 256 * i];
}

// EF[e] = leaky( ((se[u]+de[v]) / (sd[u]+dd[v])) @ W ) — tiled GEMM version
__global__ void __launch_bounds__(256)
k_edge_update_v2(const int* __restrict__ U, const int* __restrict__ V,
                 const float* __restrict__ se, const float* __restrict__ de,
                 const float* __restrict__ sd, const float* __restrict__ dd,
                 const float* __restrict__ W,
                 float* __restrict__ EF, int E) {
  __shared__ float Ws[64 * 64];
  __shared__ float Ts[64 * TPAD];
  load_W(W, Ws);
  int e0 = blockIdx.x * 64;
  int f = threadIdx.x & 63;
  int le0 = threadIdx.x >> 6;  // wave id: each wave fills rows le0, le0+4, ...
#pragma unroll
  for (int it = 0; it < 16; ++it) {
    int le = le0 + it * 4;
    int e = e0 + le;
    if (e < E) {
      int u = U[e];
      int v = V[e];
      float inv = 1.0f / (sd[u] + dd[v]);
      Ts[le * TPAD + f] = (se[u * 64 + f] + de[v * 64 + f]) * inv;
    }
  }
  __syncthreads();
  int eg = threadIdx.x >> 4;
  int cg = threadIdx.x & 15;
  float acc[4][4] = {};
  tile_gemm_4x4(Ts, Ws, eg, cg, acc);
#pragma unroll
  for (int i = 0; i < 4; ++i) {
    int e = e0 + eg * 4 + i;
    if (e < E) {
      float4 o;
      o.x = leakyf(acc[i][0]);
      o.y = leakyf(acc[i][1]);
      o.z = leakyf(acc[i][2]);
      o.w = leakyf(acc[i][3]);
      *(float4*)&EF[(size_t)e * 64 + cg * 4] = o;
    }
  }
}

// out[n] += wt * leaky( (agg[n] @ W) * nrm[n] ) — tiled GEMM version
__global__ void __launch_bounds__(256)
k_node_acc_v2(const float* __restrict__ agg, const float* __restrict__ nrm,
              const float* __restrict__ W, float wt,
              float* __restrict__ outv, int N) {
  __shared__ float Ws[64 * 64];
  __shared__ float Ts[64 * TPAD];
  load_W(W, Ws);
  int n0 = blockIdx.x * 64;
  int f = threadIdx.x & 63;
  int le0 = threadIdx.x >> 6;
#pragma unroll
  for (int it = 0; it < 16; ++it) {
    int le = le0 + it * 4;
    int n = n0 + le;
    if (n < N) Ts[le * TPAD + f] = agg[n * 64 + f];
  }
  __syncthreads();
  int eg = threadIdx.x >> 4;
  int cg = threadIdx.x & 15;
  float acc[4][4] = {};
  tile_gemm_4x4(Ts, Ws, eg, cg, acc);
#pragma unroll
  for (int i = 0; i < 4; ++i) {
    int n = n0 + eg * 4 + i;
    if (n < N) {
      float s = nrm[n];
      float* o = &outv[n * 64 + cg * 4];
      o[0] += wt * leakyf(acc[i][0] * s);
      o[1] += wt * leakyf(acc[i][1] * s);
      o[2] += wt * leakyf(acc[i][2] * s);
      o[3] += wt * leakyf(acc[i][3] * s);
    }
  }
}

__global__ void k_add(const float* __restrict__ a, float* __restrict__ b, int n) {
  int i = blockIdx.x * blockDim.x + threadIdx.x;
  if (i < n) b[i] += a[i];
}

__global__ void k_scale(float* __restrict__ a, float s, int n) {
  int i = blockIdx.x * blockDim.x + threadIdx.x;
  if (i < n) a[i] *= s;
}

extern "C" void kernel_launch(void* const* d_in, const int* in_sizes, int n_in,
                              void* d_out, int out_size, void* d_ws, size_t ws_size,
                              hipStream_t stream) {
  const float* user_emb = (const float*)d_in[0];
  const float* item_emb = (const float*)d_in[1];
  float* e_feat[3] = {(float*)d_in[2], (float*)d_in[3], (float*)d_in[4]};
  const float* node_W = (const float*)d_in[5];
  const float* edge_W = (const float*)d_in[6];
  const int* eu[3] = {(const int*)d_in[7], (const int*)d_in[9], (const int*)d_in[11]};
  const int* evv[3] = {(const int*)d_in[8], (const int*)d_in[10], (const int*)d_in[12]};
  const int Ecnt[3] = {EB_, EC_, EP_};
  const float wts[3] = {1.0f, 0.5f, 0.25f};

  float* out_src = (float*)d_out;        // [NU,64] running sum -> /3 at end
  float* out_dst = out_src + NU_ * 64;   // [NI,64]

  float* p = (float*)d_ws;
  float* src_cur = p; p += NU_ * 64;
  float* dst_cur = p; p += NI_ * 64;
  float* src_nxt = p; p += NU_ * 64;
  float* dst_nxt = p; p += NI_ * 64;
  float* agg_src = p; p += NU_ * 64;
  float* se      = p; p += NU_ * 64;
  float* agg_dst = p; p += NI_ * 64;
  float* de      = p; p += NI_ * 64;
  float* degu    = p; p += 3 * NU_;
  float* degv    = p; p += 3 * NI_;
  float* nrmu    = p; p += 3 * NU_;
  float* nrmv    = p; p += 3 * NI_;

  hipMemsetAsync(degu, 0, (size_t)(3 * NU_ + 3 * NI_) * sizeof(float), stream);
  for (int t = 0; t < 3; ++t) {
    k_deg_count<<<(Ecnt[t] + 255) / 256, 256, 0, stream>>>(
        eu[t], evv[t], degu + t * NU_, degv + t * NI_, Ecnt[t]);
  }
  for (int t = 0; t < 3; ++t) {
    k_deg_finish<<<(NU_ + 255) / 256, 256, 0, stream>>>(degu + t * NU_, nrmu + t * NU_, NU_);
    k_deg_finish<<<(NI_ + 255) / 256, 256, 0, stream>>>(degv + t * NI_, nrmv + t * NI_, NI_);
  }

  k_init_nodes<<<(NU_ * 64 + 255) / 256, 256, 0, stream>>>(user_emb, SCALE_A, src_cur, out_src, NU_ * 64);
  k_init_nodes<<<(NI_ * 64 + 255) / 256, 256, 0, stream>>>(item_emb, SCALE_A, dst_cur, out_dst, NI_ * 64);

  for (int layer = 0; layer < 2; ++layer) {
    const float* Wn = node_W + layer * 64 * 64;
    const float* We = edge_W + layer * 64 * 64;
    float escale = (layer == 0) ? SCALE_B : 1.0f;
    hipMemsetAsync(src_nxt, 0, (size_t)(NU_ + NI_) * 64 * sizeof(float), stream);
    for (int t = 0; t < 3; ++t) {
      int E = Ecnt[t];
      hipMemsetAsync(agg_src, 0, (size_t)NU_ * 128 * sizeof(float), stream);
      hipMemsetAsync(agg_dst, 0, (size_t)NI_ * 128 * sizeof(float), stream);
      k_edge_pass<<<(E * 64 + 255) / 256, 256, 0, stream>>>(
          eu[t], evv[t], e_feat[t], escale, src_cur, dst_cur,
          nrmu + t * NU_, nrmv + t * NI_, agg_dst, agg_src, se, de, E);
      k_node_acc_v2<<<(NI_ + 63) / 64, 256, 0, stream>>>(
          agg_dst, nrmv + t * NI_, Wn, wts[t], dst_nxt, NI_);
      k_node_acc_v2<<<(NU_ + 63) / 64, 256, 0, stream>>>(
          agg_src, nrmu + t * NU_, Wn, wts[t], src_nxt, NU_);
      k_edge_update_v2<<<(E + 63) / 64, 256, 0, stream>>>(
          eu[t], evv[t], se, de, degu + t * NU_, degv + t * NI_, We, e_feat[t], E);
    }
    k_add<<<(NU_ * 64 + 255) / 256, 256, 0, stream>>>(src_nxt, out_src, NU_ * 64);
    k_add<<<(NI_ * 64 + 255) / 256, 256, 0, stream>>>(dst_nxt, out_dst, NI_ * 64);
    float* tmp;
    tmp = src_cur; src_cur = src_nxt; src_nxt = tmp;
    tmp = dst_cur; dst_cur = dst_nxt; dst_nxt = tmp;
  }
  k_scale<<<((NU_ + NI_) * 64 + 255) / 256, 256, 0, stream>>>(
      out_src, 1.0f / 3.0f, (NU_ + NI_) * 64);
}